// Round 2
// baseline (268.347 us; speedup 1.0000x reference)
//
#include <hip/hip_runtime.h>
#include <hip/hip_bf16.h>

#define N_ROWS 16384
#define M_ROWS 16384
#define DIM 256

typedef __attribute__((ext_vector_type(4))) float f32x4;
typedef __attribute__((ext_vector_type(8))) short bf16x8;

__device__ inline unsigned enc_f(float f) {
  unsigned u = __float_as_uint(f);
  return (u & 0x80000000u) ? ~u : (u | 0x80000000u);
}
__device__ inline float dec_f(unsigned u) {
  unsigned b = (u & 0x80000000u) ? (u & 0x7FFFFFFFu) : ~u;
  return __uint_as_float(b);
}
__device__ inline unsigned short f2bf(float f) {
  unsigned u = __float_as_uint(f);
  u += 0x7FFFu + ((u >> 16) & 1u);
  return (unsigned short)(u >> 16);
}

// Convert one fp32 row block to bf16, compute row sum-of-squares (minus psi if given).
__global__ __launch_bounds__(256) void prep_kernel(
    const float* __restrict__ in, unsigned short* __restrict__ outb,
    float* __restrict__ out2, const float* __restrict__ psi) {
  int row  = blockIdx.x * 4 + (threadIdx.x >> 6);
  int lane = threadIdx.x & 63;
  const float4 v = *reinterpret_cast<const float4*>(in + (size_t)row * DIM + lane * 4);
  ushort4 b;
  b.x = f2bf(v.x); b.y = f2bf(v.y); b.z = f2bf(v.z); b.w = f2bf(v.w);
  *reinterpret_cast<ushort4*>(outb + (size_t)row * DIM + lane * 4) = b;
  float s = v.x * v.x + v.y * v.y + v.z * v.z + v.w * v.w;
#pragma unroll
  for (int m = 1; m < 64; m <<= 1) s += __shfl_xor(s, m, 64);
  if (lane == 0) out2[row] = psi ? (s - psi[row]) : s;
}

__global__ __launch_bounds__(256) void psimean_kernel(
    const float* __restrict__ psi, float* __restrict__ out) {
  int tid = threadIdx.x;
  double s = 0.0;
  for (int i = tid; i < M_ROWS; i += 256) s += (double)psi[i];
  __shared__ double sm[4];
#pragma unroll
  for (int m = 1; m < 64; m <<= 1) s += __shfl_xor(s, m, 64);
  if ((tid & 63) == 0) sm[tid >> 6] = s;
  __syncthreads();
  if (tid == 0) out[1] = (float)((sm[0] + sm[1] + sm[2] + sm[3]) / (double)M_ROWS);
}

// 128x128 bf16 MFMA tile, double-buffered LDS with stage-ahead pipelining,
// XOR-swizzled LDS layout, fused (r[j] - 2*dot) row-min epilogue.
__global__ __launch_bounds__(256, 2) void gemm_min_kernel(
    const unsigned short* __restrict__ xb, const unsigned short* __restrict__ yb,
    const float* __restrict__ rj, unsigned int* __restrict__ rowmin) {
  __shared__ unsigned short Atile[2][128 * 64];
  __shared__ unsigned short Btile[2][128 * 64];
  __shared__ float minbuf[128][2];

  // XCD-chunked swizzle + 16x16-tile supertiles for L2 locality.
  int bid     = blockIdx.x;
  int logical = (bid & 7) * 2048 + (bid >> 3);
  int st      = logical >> 8;
  int within  = logical & 255;
  int bi = (st >> 3) * 16 + (within >> 4);
  int bj = (st & 7) * 16 + (within & 15);
  int brow = bi * 128, bcol = bj * 128;

  int tid = threadIdx.x;
  int wid = tid >> 6, lane = tid & 63;
  int wr = wid >> 1, wc = wid & 1;  // 2x2 wave grid, 64x64 output per wave

  f32x4 acc[4][4];
#pragma unroll
  for (int i = 0; i < 4; ++i)
#pragma unroll
    for (int j = 0; j < 4; ++j) acc[i][j] = (f32x4){0.f, 0.f, 0.f, 0.f};

  // --- staging (global -> LDS, wave-uniform dest + lane*16) ---
  // LDS tile [128][64] bf16, rows of 8 x 16B slots. Swizzle: LDS[row][s]
  // holds global[row][s ^ (row&7)] -> pre-swizzle the SOURCE slot.
  const int sr  = lane >> 3;             // row within 8-row chunk (== row&7)
  const int ssl = (lane & 7) ^ sr;       // swizzled source 16B slot
  const unsigned short* gA = xb + (size_t)(brow + wid * 32 + sr) * DIM + ssl * 8;
  const unsigned short* gB = yb + (size_t)(bcol + wid * 32 + sr) * DIM + ssl * 8;

#define STAGE(buf, kt)                                                          \
  {                                                                             \
    _Pragma("unroll")                                                           \
    for (int c = 0; c < 4; ++c) {                                               \
      __builtin_amdgcn_global_load_lds(                                         \
          (const __attribute__((address_space(1))) void*)(gA + (size_t)c * 8 * DIM + (kt) * 64), \
          (__attribute__((address_space(3))) void*)(&Atile[(buf)][(wid * 32 + c * 8) * 64]), 16, 0, 0); \
      __builtin_amdgcn_global_load_lds(                                         \
          (const __attribute__((address_space(1))) void*)(gB + (size_t)c * 8 * DIM + (kt) * 64), \
          (__attribute__((address_space(3))) void*)(&Btile[(buf)][(wid * 32 + c * 8) * 64]), 16, 0, 0); \
    }                                                                           \
  }

  STAGE(0, 0);
  __syncthreads();  // drains vmcnt(0) for buf0

  const int fr = lane & 15;        // fragment row (== row&15, and row&7 == fr&7)
  const int g4 = lane >> 4;        // k-group 0..3

#pragma unroll
  for (int kt = 0; kt < 4; ++kt) {
    if (kt < 3) STAGE((kt + 1) & 1, kt + 1);  // stage ahead; drains at loop-end barrier
    const unsigned short* A = Atile[kt & 1];
    const unsigned short* B = Btile[kt & 1];
#pragma unroll
    for (int kk = 0; kk < 2; ++kk) {
      bf16x8 afr[4], bfr[4];
      const int slot = ((kk * 4 + g4) ^ (fr & 7)) * 8;  // swizzled read slot
#pragma unroll
      for (int mi = 0; mi < 4; ++mi)
        afr[mi] = *reinterpret_cast<const bf16x8*>(&A[(wr * 64 + mi * 16 + fr) * 64 + slot]);
#pragma unroll
      for (int ni = 0; ni < 4; ++ni)
        bfr[ni] = *reinterpret_cast<const bf16x8*>(&B[(wc * 64 + ni * 16 + fr) * 64 + slot]);
#pragma unroll
      for (int mi = 0; mi < 4; ++mi)
#pragma unroll
        for (int ni = 0; ni < 4; ++ni)
          acc[mi][ni] = __builtin_amdgcn_mfma_f32_16x16x32_bf16(
              afr[mi], bfr[ni], acc[mi][ni], 0, 0, 0);
    }
    __syncthreads();  // one barrier per K-iter: drains my stage loads + my ds_reads
  }
#undef STAGE

  // Epilogue: val = r[j] - 2*dot; min over this block's 128 columns.
  // C/D layout: col = lane&15, row = (lane>>4)*4 + reg (m89-verified).
  float rv[4];
#pragma unroll
  for (int ni = 0; ni < 4; ++ni) rv[ni] = rj[bcol + wc * 64 + ni * 16 + fr];

#pragma unroll
  for (int mi = 0; mi < 4; ++mi) {
#pragma unroll
    for (int r = 0; r < 4; ++r) {
      float m = rv[0] - 2.f * acc[mi][0][r];
#pragma unroll
      for (int ni = 1; ni < 4; ++ni) m = fminf(m, rv[ni] - 2.f * acc[mi][ni][r]);
#pragma unroll
      for (int s = 1; s < 16; s <<= 1) m = fminf(m, __shfl_xor(m, s, 64));
      if (fr == 0) minbuf[wr * 64 + mi * 16 + (lane >> 4) * 4 + r][wc] = m;
    }
  }
  __syncthreads();
  if (tid < 128) {
    float v = fminf(minbuf[tid][0], minbuf[tid][1]);
    atomicMin(&rowmin[brow + tid], enc_f(v));
  }
}

__global__ __launch_bounds__(256) void finish_kernel(
    const float* __restrict__ x2, const unsigned int* __restrict__ rowmin,
    float* __restrict__ out) {
  int tid = threadIdx.x;
  double s = 0.0;
  for (int i = tid; i < N_ROWS; i += 256)
    s += (double)x2[i] + (double)dec_f(rowmin[i]);
  __shared__ double sm[4];
#pragma unroll
  for (int m = 1; m < 64; m <<= 1) s += __shfl_xor(s, m, 64);
  if ((tid & 63) == 0) sm[tid >> 6] = s;
  __syncthreads();
  if (tid == 0) out[0] = (float)((sm[0] + sm[1] + sm[2] + sm[3]) / (double)N_ROWS);
}

extern "C" void kernel_launch(void* const* d_in, const int* in_sizes, int n_in,
                              void* d_out, int out_size, void* d_ws, size_t ws_size,
                              hipStream_t stream) {
  const float* x   = (const float*)d_in[0];
  const float* y   = (const float*)d_in[1];
  const float* psi = (const float*)d_in[2];
  float* out = (float*)d_out;

  char* ws = (char*)d_ws;
  unsigned short* xb = (unsigned short*)ws;                                  // 8 MB
  unsigned short* yb = (unsigned short*)(ws + (size_t)N_ROWS * DIM * 2);     // 8 MB
  float* x2 = (float*)(ws + (size_t)(N_ROWS + M_ROWS) * DIM * 2);            // 64 KB
  float* rj = x2 + N_ROWS;                                                   // 64 KB (y2 - psi)
  unsigned int* rowmin = (unsigned int*)(rj + M_ROWS);                       // 64 KB

  prep_kernel<<<N_ROWS / 4, 256, 0, stream>>>(x, xb, x2, nullptr);
  prep_kernel<<<M_ROWS / 4, 256, 0, stream>>>(y, yb, rj, psi);
  psimean_kernel<<<1, 256, 0, stream>>>(psi, out);
  hipMemsetAsync(rowmin, 0xFF, N_ROWS * sizeof(unsigned int), stream);
  gemm_min_kernel<<<(N_ROWS / 128) * (M_ROWS / 128), 256, 0, stream>>>(xb, yb, rj, rowmin);
  finish_kernel<<<1, 256, 0, stream>>>(x2, rowmin, out);
}

// Round 3
// 160.133 us; speedup vs baseline: 1.6758x; 1.6758x over previous
//
#include <hip/hip_runtime.h>
#include <hip/hip_bf16.h>

#define N_ROWS 16384
#define M_ROWS 16384
#define DIM 256
#define JT 64           // y-cols per j-iter
#define NJ 32           // j-iters per block (JT*NJ = 2048-col chunk)

typedef __attribute__((ext_vector_type(4))) float f32x4;
typedef __attribute__((ext_vector_type(8))) short bf16x8;

__device__ inline unsigned enc_f(float f) {
  unsigned u = __float_as_uint(f);
  return (u & 0x80000000u) ? ~u : (u | 0x80000000u);
}
__device__ inline float dec_f(unsigned u) {
  unsigned b = (u & 0x80000000u) ? (u & 0x7FFFFFFFu) : ~u;
  return __uint_as_float(b);
}
__device__ inline unsigned short f2bf(float f) {
  unsigned u = __float_as_uint(f);
  u += 0x7FFFu + ((u >> 16) & 1u);
  return (unsigned short)(u >> 16);
}

__global__ __launch_bounds__(256) void prep_kernel(
    const float* __restrict__ in, unsigned short* __restrict__ outb,
    float* __restrict__ out2, const float* __restrict__ psi) {
  int row  = blockIdx.x * 4 + (threadIdx.x >> 6);
  int lane = threadIdx.x & 63;
  const float4 v = *reinterpret_cast<const float4*>(in + (size_t)row * DIM + lane * 4);
  ushort4 b;
  b.x = f2bf(v.x); b.y = f2bf(v.y); b.z = f2bf(v.z); b.w = f2bf(v.w);
  *reinterpret_cast<ushort4*>(outb + (size_t)row * DIM + lane * 4) = b;
  float s = v.x * v.x + v.y * v.y + v.z * v.z + v.w * v.w;
#pragma unroll
  for (int m = 1; m < 64; m <<= 1) s += __shfl_xor(s, m, 64);
  if (lane == 0) out2[row] = psi ? (s - psi[row]) : s;
}

__global__ __launch_bounds__(256) void psimean_kernel(
    const float* __restrict__ psi, float* __restrict__ out) {
  int tid = threadIdx.x;
  double s = 0.0;
  for (int i = tid; i < M_ROWS; i += 256) s += (double)psi[i];
  __shared__ double sm[4];
#pragma unroll
  for (int m = 1; m < 64; m <<= 1) s += __shfl_xor(s, m, 64);
  if ((tid & 63) == 0) sm[tid >> 6] = s;
  __syncthreads();
  if (tid == 0) out[1] = (float)((sm[0] + sm[1] + sm[2] + sm[3]) / (double)M_ROWS);
}

// Register-resident-A, M-streaming GEMM+min.
// Block: 8 waves (512 thr), 256 x-rows x 2048 y-cols; 32 j-iters of 64 cols.
// B: 3-deep LDS ring, counted vmcnt(4), raw s_barrier, stage j+2 ahead.
__global__ __launch_bounds__(512, 2) void gemm_min_kernel(
    const unsigned short* __restrict__ xb, const unsigned short* __restrict__ yb,
    const float* __restrict__ rj, unsigned int* __restrict__ rowmin) {
  __shared__ unsigned short Bt[3][JT * DIM];  // 3 x 32 KiB, 16B-slot XOR swizzle

  const int bid    = blockIdx.x;
  const int jchunk = bid & 7;          // == XCD id under round-robin dispatch
  const int strip  = bid >> 3;
  const int brow   = strip * 256;
  const int jbase0 = jchunk * (JT * NJ);

  const int tid = threadIdx.x;
  const int w = tid >> 6, lane = tid & 63;
  const int fr = lane & 15, g4 = lane >> 4;

  // ---- A fragments in registers: rows brow + w*32 + m*16 + fr, k = ks*32 + g4*8
  bf16x8 afr[2][8];
  {
    const unsigned short* aBase = xb + (size_t)(brow + w * 32 + fr) * DIM + g4 * 8;
#pragma unroll
    for (int m = 0; m < 2; ++m)
#pragma unroll
      for (int ks = 0; ks < 8; ++ks)
        afr[m][ks] = *reinterpret_cast<const bf16x8*>(aBase + (size_t)(m * 16) * DIM + ks * 32);
  }
  __builtin_amdgcn_sched_barrier(0);

  // ---- staging: wave w stages B rows w*8+c*2+(lane>>5); 4 instrs x 1KB.
  // LDS[row][slot] = global[row][slot ^ (row&7)]  (16B slots, 32/row)
  const unsigned short* gBrow = yb + (size_t)(jbase0 + w * 8 + (lane >> 5)) * DIM;

#define STAGE(buf, j)                                                            \
  {                                                                              \
    const unsigned short* gb = gBrow + (size_t)(j) * JT * DIM;                   \
    _Pragma("unroll")                                                            \
    for (int c = 0; c < 4; ++c) {                                                \
      int sl = (lane & 31) ^ (((lane >> 5) + c * 2) & 7);                        \
      __builtin_amdgcn_global_load_lds(                                          \
          (const __attribute__((address_space(1))) void*)(gb + (size_t)(c * 2) * DIM + sl * 8), \
          (__attribute__((address_space(3))) void*)(&Bt[(buf)][(w * 8 + c * 2) * DIM]), 16, 0, 0); \
    }                                                                            \
  }

  const float* rjc = rj + jbase0;
  float rvcur[4];
#pragma unroll
  for (int n = 0; n < 4; ++n) rvcur[n] = rjc[n * 16 + fr];
  __builtin_amdgcn_sched_barrier(0);
  STAGE(0, 0);
  STAGE(1, 1);

  float mx[2][4];
#pragma unroll
  for (int m = 0; m < 2; ++m)
#pragma unroll
    for (int r = 0; r < 4; ++r) mx[m][r] = -3.4e38f;

  int rb = 0;  // ring read index
#pragma unroll 1
  for (int j = 0; j < NJ; ++j) {
    if (j == NJ - 1) { asm volatile("s_waitcnt vmcnt(0)" ::: "memory"); }
    else             { asm volatile("s_waitcnt vmcnt(4)" ::: "memory"); }
    __builtin_amdgcn_sched_barrier(0);
    __builtin_amdgcn_s_barrier();
    __builtin_amdgcn_sched_barrier(0);

    // acc init encodes -rv/2 so final value = -2*acc = rv - 2*dot
    f32x4 acc[2][4];
#pragma unroll
    for (int m = 0; m < 2; ++m)
#pragma unroll
      for (int n = 0; n < 4; ++n) {
        float v = -0.5f * rvcur[n];
        acc[m][n] = (f32x4){v, v, v, v};
      }

    float rvnext[4] = {0.f, 0.f, 0.f, 0.f};
    if (j + 1 < NJ) {
#pragma unroll
      for (int n = 0; n < 4; ++n) rvnext[n] = rjc[(j + 1) * JT + n * 16 + fr];
    }
    __builtin_amdgcn_sched_barrier(0);
    if (j + 2 < NJ) {
      int sb = rb + 2; if (sb >= 3) sb -= 3;
      STAGE(sb, j + 2);
    }
    __builtin_amdgcn_sched_barrier(0);

    const unsigned short* B = &Bt[rb][0];
    __builtin_amdgcn_s_setprio(1);
#pragma unroll
    for (int ks = 0; ks < 8; ++ks) {
      bf16x8 bfr[4];
#pragma unroll
      for (int n = 0; n < 4; ++n)
        bfr[n] = *reinterpret_cast<const bf16x8*>(
            &B[(n * 16 + fr) * DIM + (((ks * 4 + g4) ^ (fr & 7)) * 8)]);
#pragma unroll
      for (int m = 0; m < 2; ++m)
#pragma unroll
        for (int n = 0; n < 4; ++n)
          acc[m][n] = __builtin_amdgcn_mfma_f32_16x16x32_bf16(
              afr[m][ks], bfr[n], acc[m][n], 0, 0, 0);
    }
    __builtin_amdgcn_s_setprio(0);

#pragma unroll
    for (int m = 0; m < 2; ++m)
#pragma unroll
      for (int n = 0; n < 4; ++n)
#pragma unroll
        for (int r = 0; r < 4; ++r)
          mx[m][r] = fmaxf(mx[m][r], acc[m][n][r]);

    if (j + 1 < NJ) {
#pragma unroll
      for (int n = 0; n < 4; ++n) rvcur[n] = rvnext[n];
    }
    rb = rb + 1; if (rb >= 3) rb -= 3;
  }
#undef STAGE

  // Row-min over chunk: reduce max over the 16 fr-lanes, then one atomic per row.
#pragma unroll
  for (int m = 0; m < 2; ++m)
#pragma unroll
    for (int r = 0; r < 4; ++r) {
      float v = mx[m][r];
#pragma unroll
      for (int s = 1; s < 16; s <<= 1) v = fmaxf(v, __shfl_xor(v, s, 64));
      if (fr == 0) {
        int row = brow + w * 32 + m * 16 + g4 * 4 + r;
        atomicMin(&rowmin[row], enc_f(-2.0f * v));
      }
    }
}

__global__ __launch_bounds__(256) void finish_kernel(
    const float* __restrict__ x2, const unsigned int* __restrict__ rowmin,
    float* __restrict__ out) {
  int tid = threadIdx.x;
  double s = 0.0;
  for (int i = tid; i < N_ROWS; i += 256)
    s += (double)x2[i] + (double)dec_f(rowmin[i]);
  __shared__ double sm[4];
#pragma unroll
  for (int m = 1; m < 64; m <<= 1) s += __shfl_xor(s, m, 64);
  if ((tid & 63) == 0) sm[tid >> 6] = s;
  __syncthreads();
  if (tid == 0) out[0] = (float)((sm[0] + sm[1] + sm[2] + sm[3]) / (double)N_ROWS);
}

extern "C" void kernel_launch(void* const* d_in, const int* in_sizes, int n_in,
                              void* d_out, int out_size, void* d_ws, size_t ws_size,
                              hipStream_t stream) {
  const float* x   = (const float*)d_in[0];
  const float* y   = (const float*)d_in[1];
  const float* psi = (const float*)d_in[2];
  float* out = (float*)d_out;

  char* ws = (char*)d_ws;
  unsigned short* xb = (unsigned short*)ws;                                  // 8 MB
  unsigned short* yb = (unsigned short*)(ws + (size_t)N_ROWS * DIM * 2);     // 8 MB
  float* x2 = (float*)(ws + (size_t)(N_ROWS + M_ROWS) * DIM * 2);            // 64 KB
  float* rj = x2 + N_ROWS;                                                   // 64 KB (y2 - psi)
  unsigned int* rowmin = (unsigned int*)(rj + M_ROWS);                       // 64 KB

  prep_kernel<<<N_ROWS / 4, 256, 0, stream>>>(x, xb, x2, nullptr);
  prep_kernel<<<M_ROWS / 4, 256, 0, stream>>>(y, yb, rj, psi);
  psimean_kernel<<<1, 256, 0, stream>>>(psi, out);
  hipMemsetAsync(rowmin, 0xFF, N_ROWS * sizeof(unsigned int), stream);
  gemm_min_kernel<<<(N_ROWS / 256) * 8, 512, 0, stream>>>(xb, yb, rj, rowmin);
  finish_kernel<<<1, 256, 0, stream>>>(x2, rowmin, out);
}

// Round 4
// 149.085 us; speedup vs baseline: 1.8000x; 1.0741x over previous
//
#include <hip/hip_runtime.h>
#include <hip/hip_bf16.h>

#define N_ROWS 16384
#define M_ROWS 16384
#define DIM 256
#define JT 32           // y-cols per j-iter
#define NJ 64           // j-iters per block (JT*NJ = 2048-col chunk)

typedef __attribute__((ext_vector_type(4))) float f32x4;
typedef __attribute__((ext_vector_type(8))) short bf16x8;

__device__ inline unsigned enc_f(float f) {
  unsigned u = __float_as_uint(f);
  return (u & 0x80000000u) ? ~u : (u | 0x80000000u);
}
__device__ inline float dec_f(unsigned u) {
  unsigned b = (u & 0x80000000u) ? (u & 0x7FFFFFFFu) : ~u;
  return __uint_as_float(b);
}
__device__ inline unsigned short f2bf(float f) {
  unsigned u = __float_as_uint(f);
  u += 0x7FFFu + ((u >> 16) & 1u);
  return (unsigned short)(u >> 16);
}

// Fused prep: blocks [0,4096) convert x -> xb + x2 + rowmin init;
// blocks [4096,8192) convert y -> yb + (y2 - psi).
__global__ __launch_bounds__(256) void prep_kernel(
    const float* __restrict__ x, const float* __restrict__ y,
    const float* __restrict__ psi,
    unsigned short* __restrict__ xb, unsigned short* __restrict__ yb,
    float* __restrict__ x2, float* __restrict__ rj,
    unsigned int* __restrict__ rowmin) {
  int bid  = blockIdx.x;
  int isY  = bid >= (N_ROWS / 4);
  int rb   = isY ? bid - N_ROWS / 4 : bid;
  int row  = rb * 4 + (threadIdx.x >> 6);
  int lane = threadIdx.x & 63;
  const float* in = isY ? y : x;
  unsigned short* outb = isY ? yb : xb;
  const float4 v = *reinterpret_cast<const float4*>(in + (size_t)row * DIM + lane * 4);
  ushort4 b;
  b.x = f2bf(v.x); b.y = f2bf(v.y); b.z = f2bf(v.z); b.w = f2bf(v.w);
  *reinterpret_cast<ushort4*>(outb + (size_t)row * DIM + lane * 4) = b;
  float s = v.x * v.x + v.y * v.y + v.z * v.z + v.w * v.w;
#pragma unroll
  for (int m = 1; m < 64; m <<= 1) s += __shfl_xor(s, m, 64);
  if (lane == 0) {
    if (isY) rj[row] = s - psi[row];
    else { x2[row] = s; rowmin[row] = 0xFFFFFFFFu; }
  }
}

// Register-resident-A (64 rows/wave), M-streaming GEMM+min.
// Block: 4 waves (256 thr), 256 x-rows x 2048 y-cols; 64 j-iters of 32 cols.
// B: 3-deep LDS ring (16KB tiles), counted vmcnt(4), raw s_barrier, stage j+2.
__global__ __launch_bounds__(256, 2) void gemm_min_kernel(
    const unsigned short* __restrict__ xb, const unsigned short* __restrict__ yb,
    const float* __restrict__ rj, unsigned int* __restrict__ rowmin) {
  __shared__ unsigned short Bt[3][JT * DIM];  // 3 x 16 KiB, 16B-slot XOR swizzle

  const int bid    = blockIdx.x;       // 512 blocks, 2 per CU
  const int jchunk = bid & 7;          // == XCD id under round-robin dispatch
  const int strip  = bid >> 3;         // 0..63
  const int brow   = strip * 256;
  const int jbase0 = jchunk * (JT * NJ);

  const int tid = threadIdx.x;
  const int w = tid >> 6, lane = tid & 63;
  const int fr = lane & 15, g4 = lane >> 4;

  // ---- A fragments in registers: rows brow + w*64 + m*16 + fr, k = ks*32 + g4*8
  bf16x8 afr[4][8];
  {
    const unsigned short* aBase = xb + (size_t)(brow + w * 64 + fr) * DIM + g4 * 8;
#pragma unroll
    for (int m = 0; m < 4; ++m)
#pragma unroll
      for (int ks = 0; ks < 8; ++ks)
        afr[m][ks] = *reinterpret_cast<const bf16x8*>(aBase + (size_t)(m * 16) * DIM + ks * 32);
  }
  __builtin_amdgcn_sched_barrier(0);

  // ---- staging: wave w stages B rows w*8 + c*2 + (lane>>5); 4 instrs x 1KB.
  // LDS[row][slot] = global[row][slot ^ (row&7)]  (16B slots, 32/row)
  const unsigned short* gBrow = yb + (size_t)(jbase0 + w * 8 + (lane >> 5)) * DIM;

#define STAGE(buf, j)                                                            \
  {                                                                              \
    const unsigned short* gb = gBrow + (size_t)(j) * JT * DIM;                   \
    _Pragma("unroll")                                                            \
    for (int c = 0; c < 4; ++c) {                                                \
      int sl = (lane & 31) ^ (((lane >> 5) + c * 2) & 7);                        \
      __builtin_amdgcn_global_load_lds(                                          \
          (const __attribute__((address_space(1))) void*)(gb + (size_t)(c * 2) * DIM + sl * 8), \
          (__attribute__((address_space(3))) void*)(&Bt[(buf)][(w * 8 + c * 2) * DIM]), 16, 0, 0); \
    }                                                                            \
  }

  STAGE(0, 0);
  STAGE(1, 1);

  const float* rjc = rj + jbase0;
  float mn[4][4];
#pragma unroll
  for (int m = 0; m < 4; ++m)
#pragma unroll
    for (int r = 0; r < 4; ++r) mn[m][r] = 3.4e38f;

  int rb = 0;  // ring read index
#pragma unroll 1
  for (int j = 0; j < NJ; ++j) {
    if (j == NJ - 1) { asm volatile("s_waitcnt vmcnt(0)" ::: "memory"); }
    else             { asm volatile("s_waitcnt vmcnt(4)" ::: "memory"); }
    __builtin_amdgcn_sched_barrier(0);
    __builtin_amdgcn_s_barrier();
    __builtin_amdgcn_sched_barrier(0);

    // rv loads issued early; consumed only at iter end (latency hidden by MFMA).
    float rv0 = rjc[j * JT + fr];
    float rv1 = rjc[j * JT + 16 + fr];
    __builtin_amdgcn_sched_barrier(0);
    if (j + 2 < NJ) {
      int sb = rb + 2; if (sb >= 3) sb -= 3;
      STAGE(sb, j + 2);
    }
    __builtin_amdgcn_sched_barrier(0);

    f32x4 acc[4][2];
#pragma unroll
    for (int m = 0; m < 4; ++m)
#pragma unroll
      for (int n = 0; n < 2; ++n) acc[m][n] = (f32x4){0.f, 0.f, 0.f, 0.f};

    const unsigned short* B = &Bt[rb][0];
    __builtin_amdgcn_s_setprio(1);
#pragma unroll
    for (int ks = 0; ks < 8; ++ks) {
      bf16x8 bfr[2];
#pragma unroll
      for (int n = 0; n < 2; ++n)
        bfr[n] = *reinterpret_cast<const bf16x8*>(
            &B[(n * 16 + fr) * DIM + (((ks * 4 + g4) ^ (fr & 7)) * 8)]);
#pragma unroll
      for (int m = 0; m < 4; ++m)
#pragma unroll
        for (int n = 0; n < 2; ++n)
          acc[m][n] = __builtin_amdgcn_mfma_f32_16x16x32_bf16(
              afr[m][ks], bfr[n], acc[m][n], 0, 0, 0);
    }
    __builtin_amdgcn_s_setprio(0);

    // fold: val = rv - 2*dot ; running min
#pragma unroll
    for (int m = 0; m < 4; ++m)
#pragma unroll
      for (int r = 0; r < 4; ++r) {
        mn[m][r] = fminf(mn[m][r], fmaf(-2.f, acc[m][0][r], rv0));
        mn[m][r] = fminf(mn[m][r], fmaf(-2.f, acc[m][1][r], rv1));
      }
    rb = rb + 1; if (rb >= 3) rb -= 3;
  }
#undef STAGE

  // Row-min over chunk: reduce min over the 16 fr-lanes, then one atomic per row.
#pragma unroll
  for (int m = 0; m < 4; ++m)
#pragma unroll
    for (int r = 0; r < 4; ++r) {
      float v = mn[m][r];
#pragma unroll
      for (int s = 1; s < 16; s <<= 1) v = fminf(v, __shfl_xor(v, s, 64));
      if (fr == 0) {
        int row = brow + w * 64 + m * 16 + g4 * 4 + r;
        atomicMin(&rowmin[row], enc_f(v));
      }
    }
}

__global__ __launch_bounds__(256) void finish_kernel(
    const float* __restrict__ x2, const unsigned int* __restrict__ rowmin,
    const float* __restrict__ psi, float* __restrict__ out) {
  int tid = threadIdx.x;
  double s0 = 0.0, s1 = 0.0;
  for (int i = tid; i < N_ROWS; i += 256) {
    s0 += (double)x2[i] + (double)dec_f(rowmin[i]);
    s1 += (double)psi[i];
  }
  __shared__ double sm0[4], sm1[4];
#pragma unroll
  for (int m = 1; m < 64; m <<= 1) { s0 += __shfl_xor(s0, m, 64); s1 += __shfl_xor(s1, m, 64); }
  if ((tid & 63) == 0) { sm0[tid >> 6] = s0; sm1[tid >> 6] = s1; }
  __syncthreads();
  if (tid == 0) {
    out[0] = (float)((sm0[0] + sm0[1] + sm0[2] + sm0[3]) / (double)N_ROWS);
    out[1] = (float)((sm1[0] + sm1[1] + sm1[2] + sm1[3]) / (double)M_ROWS);
  }
}

extern "C" void kernel_launch(void* const* d_in, const int* in_sizes, int n_in,
                              void* d_out, int out_size, void* d_ws, size_t ws_size,
                              hipStream_t stream) {
  const float* x   = (const float*)d_in[0];
  const float* y   = (const float*)d_in[1];
  const float* psi = (const float*)d_in[2];
  float* out = (float*)d_out;

  char* ws = (char*)d_ws;
  unsigned short* xb = (unsigned short*)ws;                                  // 8 MB
  unsigned short* yb = (unsigned short*)(ws + (size_t)N_ROWS * DIM * 2);     // 8 MB
  float* x2 = (float*)(ws + (size_t)(N_ROWS + M_ROWS) * DIM * 2);            // 64 KB
  float* rj = x2 + N_ROWS;                                                   // 64 KB (y2 - psi)
  unsigned int* rowmin = (unsigned int*)(rj + M_ROWS);                       // 64 KB

  prep_kernel<<<(N_ROWS + M_ROWS) / 4, 256, 0, stream>>>(x, y, psi, xb, yb, x2, rj, rowmin);
  gemm_min_kernel<<<(N_ROWS / 256) * 8, 256, 0, stream>>>(xb, yb, rj, rowmin);
  finish_kernel<<<1, 256, 0, stream>>>(x2, rowmin, psi, out);
}

// Round 5
// 146.099 us; speedup vs baseline: 1.8367x; 1.0204x over previous
//
#include <hip/hip_runtime.h>
#include <hip/hip_bf16.h>

#define N_ROWS 16384
#define M_ROWS 16384
#define DIM 256
#define JT 32           // y-cols per j-iter
#define NJ 64           // j-iters per block (JT*NJ = 2048-col chunk)

typedef __attribute__((ext_vector_type(4))) float f32x4;
typedef __attribute__((ext_vector_type(8))) short bf16x8;

__device__ inline unsigned enc_f(float f) {
  unsigned u = __float_as_uint(f);
  return (u & 0x80000000u) ? ~u : (u | 0x80000000u);
}
__device__ inline float dec_f(unsigned u) {
  unsigned b = (u & 0x80000000u) ? (u & 0x7FFFFFFFu) : ~u;
  return __uint_as_float(b);
}
__device__ inline unsigned short f2bf(float f) {
  unsigned u = __float_as_uint(f);
  u += 0x7FFFu + ((u >> 16) & 1u);
  return (unsigned short)(u >> 16);
}

// Fused prep: blocks [0,4096) convert x -> xb + x2 + rowmin init;
// blocks [4096,8192) convert y -> yb + (y2 - psi).
__global__ __launch_bounds__(256) void prep_kernel(
    const float* __restrict__ x, const float* __restrict__ y,
    const float* __restrict__ psi,
    unsigned short* __restrict__ xb, unsigned short* __restrict__ yb,
    float* __restrict__ x2, float* __restrict__ rj,
    unsigned int* __restrict__ rowmin) {
  int bid  = blockIdx.x;
  int isY  = bid >= (N_ROWS / 4);
  int rb   = isY ? bid - N_ROWS / 4 : bid;
  int row  = rb * 4 + (threadIdx.x >> 6);
  int lane = threadIdx.x & 63;
  const float* in = isY ? y : x;
  unsigned short* outb = isY ? yb : xb;
  const float4 v = *reinterpret_cast<const float4*>(in + (size_t)row * DIM + lane * 4);
  ushort4 b;
  b.x = f2bf(v.x); b.y = f2bf(v.y); b.z = f2bf(v.z); b.w = f2bf(v.w);
  *reinterpret_cast<ushort4*>(outb + (size_t)row * DIM + lane * 4) = b;
  float s = v.x * v.x + v.y * v.y + v.z * v.z + v.w * v.w;
#pragma unroll
  for (int m = 1; m < 64; m <<= 1) s += __shfl_xor(s, m, 64);
  if (lane == 0) {
    if (isY) rj[row] = s - psi[row];
    else { x2[row] = s; rowmin[row] = 0xFFFFFFFFu; }
  }
}

// Register-resident-A (64 rows/wave), M-streaming GEMM+min.
// Block: 4 waves (256 thr), 256 x-rows x 2048 y-cols; 64 j-iters of 32 cols.
// B: 3-deep LDS ring (16KB tiles), counted vmcnt(4), raw s_barrier, stage j+2.
// A fragments pinned in VGPRs via opaque asm (defeats rematerialization).
__global__ __launch_bounds__(256, 2) void gemm_min_kernel(
    const unsigned short* __restrict__ xb, const unsigned short* __restrict__ yb,
    const float* __restrict__ rj, unsigned int* __restrict__ rowmin) {
  __shared__ unsigned short Bt[3][JT * DIM];  // 3 x 16 KiB, 16B-slot XOR swizzle

  const int bid    = blockIdx.x;       // 512 blocks, 2 per CU
  const int jchunk = bid & 7;          // == XCD id under round-robin dispatch
  const int strip  = bid >> 3;         // 0..63
  const int brow   = strip * 256;
  const int jbase0 = jchunk * (JT * NJ);

  const int tid = threadIdx.x;
  const int w = tid >> 6, lane = tid & 63;
  const int fr = lane & 15, g4 = lane >> 4;

  // ---- A fragments in registers: rows brow + w*64 + m*16 + fr, k = ks*32 + g4*8
  bf16x8 afr[4][8];
  {
    const unsigned short* aBase = xb + (size_t)(brow + w * 64 + fr) * DIM + g4 * 8;
#pragma unroll
    for (int m = 0; m < 4; ++m)
#pragma unroll
      for (int ks = 0; ks < 8; ++ks) {
        afr[m][ks] = *reinterpret_cast<const bf16x8*>(aBase + (size_t)(m * 16) * DIM + ks * 32);
        // Opaque pin: value becomes asm-defined -> cannot be rematerialized
        // from global memory inside the j-loop; must stay in VGPRs.
        asm volatile("" : "+v"(afr[m][ks]));
      }
  }
  __builtin_amdgcn_sched_barrier(0);

  // ---- staging: wave w stages B rows w*8 + c*2 + (lane>>5); 4 instrs x 1KB.
  // LDS[row][slot] = global[row][slot ^ (row&7)]  (16B slots, 32/row)
  const unsigned short* gBrow = yb + (size_t)(jbase0 + w * 8 + (lane >> 5)) * DIM;

#define STAGE(buf, j)                                                            \
  {                                                                              \
    const unsigned short* gb = gBrow + (size_t)(j) * JT * DIM;                   \
    _Pragma("unroll")                                                            \
    for (int c = 0; c < 4; ++c) {                                                \
      int sl = (lane & 31) ^ (((lane >> 5) + c * 2) & 7);                        \
      __builtin_amdgcn_global_load_lds(                                          \
          (const __attribute__((address_space(1))) void*)(gb + (size_t)(c * 2) * DIM + sl * 8), \
          (__attribute__((address_space(3))) void*)(&Bt[(buf)][(w * 8 + c * 2) * DIM]), 16, 0, 0); \
    }                                                                            \
  }

  STAGE(0, 0);
  STAGE(1, 1);

  const float* rjc = rj + jbase0;
  float mn[4][4];
#pragma unroll
  for (int m = 0; m < 4; ++m)
#pragma unroll
    for (int r = 0; r < 4; ++r) mn[m][r] = 3.4e38f;

  int rb = 0;  // ring read index
#pragma unroll 1
  for (int j = 0; j < NJ; ++j) {
    if (j == NJ - 1) { asm volatile("s_waitcnt vmcnt(0)" ::: "memory"); }
    else             { asm volatile("s_waitcnt vmcnt(4)" ::: "memory"); }
    __builtin_amdgcn_sched_barrier(0);
    __builtin_amdgcn_s_barrier();
    __builtin_amdgcn_sched_barrier(0);

    // rv loads issued early; consumed only at iter end (latency hidden by MFMA).
    float rv0 = rjc[j * JT + fr];
    float rv1 = rjc[j * JT + 16 + fr];
    __builtin_amdgcn_sched_barrier(0);
    if (j + 2 < NJ) {
      int sb = rb + 2; if (sb >= 3) sb -= 3;
      STAGE(sb, j + 2);
    }
    __builtin_amdgcn_sched_barrier(0);

    f32x4 acc[4][2];
#pragma unroll
    for (int m = 0; m < 4; ++m)
#pragma unroll
      for (int n = 0; n < 2; ++n) acc[m][n] = (f32x4){0.f, 0.f, 0.f, 0.f};

    const unsigned short* B = &Bt[rb][0];
    __builtin_amdgcn_s_setprio(1);
#pragma unroll
    for (int ks = 0; ks < 8; ++ks) {
      bf16x8 bfr[2];
#pragma unroll
      for (int n = 0; n < 2; ++n)
        bfr[n] = *reinterpret_cast<const bf16x8*>(
            &B[(n * 16 + fr) * DIM + (((ks * 4 + g4) ^ (fr & 7)) * 8)]);
#pragma unroll
      for (int m = 0; m < 4; ++m)
#pragma unroll
        for (int n = 0; n < 2; ++n)
          acc[m][n] = __builtin_amdgcn_mfma_f32_16x16x32_bf16(
              afr[m][ks], bfr[n], acc[m][n], 0, 0, 0);
    }
    __builtin_amdgcn_s_setprio(0);

    // fold: val = rv - 2*dot ; running min
#pragma unroll
    for (int m = 0; m < 4; ++m)
#pragma unroll
      for (int r = 0; r < 4; ++r) {
        mn[m][r] = fminf(mn[m][r], fmaf(-2.f, acc[m][0][r], rv0));
        mn[m][r] = fminf(mn[m][r], fmaf(-2.f, acc[m][1][r], rv1));
      }
    rb = rb + 1; if (rb >= 3) rb -= 3;
  }
#undef STAGE

  // Row-min over chunk: reduce min over the 16 fr-lanes, then one atomic per row.
#pragma unroll
  for (int m = 0; m < 4; ++m)
#pragma unroll
    for (int r = 0; r < 4; ++r) {
      float v = mn[m][r];
#pragma unroll
      for (int s = 1; s < 16; s <<= 1) v = fminf(v, __shfl_xor(v, s, 64));
      if (fr == 0) {
        int row = brow + w * 64 + m * 16 + g4 * 4 + r;
        atomicMin(&rowmin[row], enc_f(v));
      }
    }
}

__global__ __launch_bounds__(256) void finish_kernel(
    const float* __restrict__ x2, const unsigned int* __restrict__ rowmin,
    const float* __restrict__ psi, float* __restrict__ out) {
  int tid = threadIdx.x;
  double s0 = 0.0, s1 = 0.0;
  for (int i = tid; i < N_ROWS; i += 256) {
    s0 += (double)x2[i] + (double)dec_f(rowmin[i]);
    s1 += (double)psi[i];
  }
  __shared__ double sm0[4], sm1[4];
#pragma unroll
  for (int m = 1; m < 64; m <<= 1) { s0 += __shfl_xor(s0, m, 64); s1 += __shfl_xor(s1, m, 64); }
  if ((tid & 63) == 0) { sm0[tid >> 6] = s0; sm1[tid >> 6] = s1; }
  __syncthreads();
  if (tid == 0) {
    out[0] = (float)((sm0[0] + sm0[1] + sm0[2] + sm0[3]) / (double)N_ROWS);
    out[1] = (float)((sm1[0] + sm1[1] + sm1[2] + sm1[3]) / (double)M_ROWS);
  }
}

extern "C" void kernel_launch(void* const* d_in, const int* in_sizes, int n_in,
                              void* d_out, int out_size, void* d_ws, size_t ws_size,
                              hipStream_t stream) {
  const float* x   = (const float*)d_in[0];
  const float* y   = (const float*)d_in[1];
  const float* psi = (const float*)d_in[2];
  float* out = (float*)d_out;

  char* ws = (char*)d_ws;
  unsigned short* xb = (unsigned short*)ws;                                  // 8 MB
  unsigned short* yb = (unsigned short*)(ws + (size_t)N_ROWS * DIM * 2);     // 8 MB
  float* x2 = (float*)(ws + (size_t)(N_ROWS + M_ROWS) * DIM * 2);            // 64 KB
  float* rj = x2 + N_ROWS;                                                   // 64 KB (y2 - psi)
  unsigned int* rowmin = (unsigned int*)(rj + M_ROWS);                       // 64 KB

  prep_kernel<<<(N_ROWS + M_ROWS) / 4, 256, 0, stream>>>(x, y, psi, xb, yb, x2, rj, rowmin);
  gemm_min_kernel<<<(N_ROWS / 256) * 8, 256, 0, stream>>>(xb, yb, rj, rowmin);
  finish_kernel<<<1, 256, 0, stream>>>(x2, rowmin, psi, out);
}